// Round 19
// baseline (828.003 us; speedup 1.0000x reference)
//
#include <hip/hip_runtime.h>
#include <hip/hip_bf16.h>

#define BB 16
#define SS 512
#define DD 1024
#define HH 16
#define LL 4
#define DHH 64
#define GK 1024

typedef __attribute__((ext_vector_type(8))) short short8;
typedef __attribute__((ext_vector_type(4))) float f32x4;
typedef __attribute__((ext_vector_type(8))) _Float16 half8;

__device__ __forceinline__ unsigned short f2bf(float f) {
  union { float f; unsigned int u; } v; v.f = f;
  unsigned int r = v.u + 0x7FFFu + ((v.u >> 16) & 1u);
  return (unsigned short)(r >> 16);
}
__device__ __forceinline__ float bf2f(unsigned short u) {
  union { unsigned int i; float f; } v; v.i = ((unsigned)u) << 16; return v.f;
}

__device__ __forceinline__ float wave_max(float v) {
#pragma unroll
  for (int off = 32; off > 0; off >>= 1) v = fmaxf(v, __shfl_xor(v, off));
  return v;
}
__device__ __forceinline__ float wave_sum(float v) {
#pragma unroll
  for (int off = 32; off > 0; off >>= 1) v += __shfl_xor(v, off);
  return v;
}
__device__ __forceinline__ float half_max(float v) {   // width-32 segment
#pragma unroll
  for (int off = 16; off > 0; off >>= 1) v = fmaxf(v, __shfl_xor(v, off));
  return v;
}
__device__ __forceinline__ float half_sum(float v) {
#pragma unroll
  for (int off = 16; off > 0; off >>= 1) v += __shfl_xor(v, off);
  return v;
}

// global -> LDS direct 16B copy. LDS dest is wave-uniform base + lane*16.
__device__ __forceinline__ void gl16(const void* g, void* l) {
  __builtin_amdgcn_global_load_lds(
      (const __attribute__((address_space(1))) unsigned int*)(uintptr_t)g,
      (__attribute__((address_space(3))) unsigned int*)(unsigned int)(uintptr_t)l,
      16, 0, 0);
}

// ---------------- all weights fp32 -> bf16 in ONE launch ----------------
__global__ __launch_bounds__(256) void k_w2bf_all(
    const float* __restrict__ wq, const float* __restrict__ wv,
    const float* __restrict__ wo, unsigned short* __restrict__ oqv,
    unsigned short* __restrict__ oo) {
  size_t i4 = ((size_t)blockIdx.x * 256 + threadIdx.x) * 4;
  const size_t QV = (size_t)2 * LL * DD * DD;
  const float* src;
  unsigned short* dst;
  if (i4 < QV) {
    size_t l = i4 >> 21;
    size_t r = i4 & ((1u << 21) - 1);
    src = (r < (1u << 20)) ? wq + (l << 20) + r
                           : wv + (l << 20) + (r - (1u << 20));
    dst = oqv + i4;
  } else {
    size_t j = i4 - QV;
    src = wo + j;
    dst = oo + j;
  }
  float4 v = *(const float4*)src;
  uint2 pk;
  pk.x = (unsigned)f2bf(v.x) | ((unsigned)f2bf(v.y) << 16);
  pk.y = (unsigned)f2bf(v.z) | ((unsigned)f2bf(v.w) << 16);
  *(uint2*)dst = pk;
}

// ---------------- q0 = bf16(x + positional encoding) ----------------
__global__ __launch_bounds__(256) void k_add_pe(const float* __restrict__ x,
                                                unsigned short* __restrict__ outb) {
  size_t i4 = ((size_t)blockIdx.x * 256 + threadIdx.x) * 4;
  int d0 = (int)(i4 & (DD - 1));
  int s = (int)((i4 >> 10) & (SS - 1));
  float4 xv = *(const float4*)(x + i4);
  int ip0 = d0 >> 1;
  float f0 = __expf((float)ip0 * -0.017988946039016f);
  float f1 = __expf((float)(ip0 + 1) * -0.017988946039016f);
  float s0v, c0v, s1v, c1v;
  __sincosf((float)s * f0, &s0v, &c0v);
  __sincosf((float)s * f1, &s1v, &c1v);
  float o0 = xv.x + s0v, o1 = xv.y + c0v, o2 = xv.z + s1v, o3 = xv.w + c1v;
  uint2 pk;
  pk.x = (unsigned)f2bf(o0) | ((unsigned)f2bf(o1) << 16);
  pk.y = (unsigned)f2bf(o2) | ((unsigned)f2bf(o3) << 16);
  *(uint2*)(outb + i4) = pk;
}

// ---------------- C = A[M,K]bf16 @ W[N,K]^T bf16 + bias ----------------
// MODE 0: bf16 [M,1024].
// MODE 3: fused QV (N=2048): col<1024 -> bf16 Qbf; col>=1024 -> transposed VtB.
// XCD L2-locality mapping: each XCD owns a contiguous 8-M-tile panel.
template <int MODE>
__global__ __launch_bounds__(256) void k_gemm(
    const unsigned short* __restrict__ A, const unsigned short* __restrict__ W,
    const float* __restrict__ bias, const float* __restrict__ bias2,
    void* __restrict__ out, void* __restrict__ out2) {
  __shared__ unsigned short As[2][128 * 32];
  __shared__ unsigned short Bs[2][128 * 32];
  const int tid = threadIdx.x;
  const int lane = tid & 63;
  const int w = tid >> 6;
  const int wr = w >> 1, wc = w & 1;
  const int fr = lane & 15, fq = lane >> 4;

  const int bid = blockIdx.x;
  const int bm = ((bid & 7) * 8 + ((bid >> 3) & 7)) * 128;
  const int bn = (bid >> 6) * 128;

  f32x4 acc[4][4] = {};

  const unsigned short* ga = A + (size_t)(bm + w * 16 + (lane >> 2)) * GK + (lane & 3) * 8;
  const unsigned short* gb = W + (size_t)(bn + w * 16 + (lane >> 2)) * GK + (lane & 3) * 8;

  auto STAGE = [&](int buf, int k0) {
    unsigned short* la = As[buf] + w * 512;
    unsigned short* lb = Bs[buf] + w * 512;
    gl16(ga + k0, la);
    gl16(ga + 64 * GK + k0, la + 2048);
    gl16(gb + k0, lb);
    gl16(gb + 64 * GK + k0, lb + 2048);
  };

  STAGE(0, 0);
  __syncthreads();
  int cur = 0;
  for (int k0 = 0; k0 < GK; k0 += 32) {
    if (k0 + 32 < GK) STAGE(cur ^ 1, k0 + 32);
    short8 af[4], bf[4];
#pragma unroll
    for (int m = 0; m < 4; ++m)
      af[m] = *(const short8*)(As[cur] + (wr * 64 + m * 16 + fr) * 32 + fq * 8);
#pragma unroll
    for (int n = 0; n < 4; ++n)
      bf[n] = *(const short8*)(Bs[cur] + (wc * 64 + n * 16 + fr) * 32 + fq * 8);
#pragma unroll
    for (int m = 0; m < 4; ++m)
#pragma unroll
      for (int n = 0; n < 4; ++n)
        acc[m][n] = __builtin_amdgcn_mfma_f32_16x16x32_bf16(af[m], bf[n], acc[m][n], 0, 0, 0);
    __syncthreads();
    cur ^= 1;
  }

#pragma unroll
  for (int m = 0; m < 4; ++m) {
    const int row0 = bm + wr * 64 + m * 16 + fq * 4;
#pragma unroll
    for (int n = 0; n < 4; ++n) {
      const int col = bn + wc * 64 + n * 16 + fr;
      if constexpr (MODE == 0) {
        const float bsv = bias[col];
        unsigned short* o = (unsigned short*)out;
#pragma unroll
        for (int r = 0; r < 4; ++r)
          o[(size_t)(row0 + r) * DD + col] = f2bf(acc[m][n][r] + bsv);
      } else {  // MODE 3: fused QV
        if (col < DD) {
          const float bsv = bias[col];
          unsigned short* o = (unsigned short*)out;
#pragma unroll
          for (int r = 0; r < 4; ++r)
            o[(size_t)(row0 + r) * DD + col] = f2bf(acc[m][n][r] + bsv);
        } else {
          const int c2 = col - DD;
          const float bsv = bias2[c2];
          unsigned short* o = (unsigned short*)out2;
          const int bi = row0 >> 9, si = row0 & (SS - 1);
          uint2 pk;
          pk.x = (unsigned)f2bf(acc[m][n][0] + bsv) | ((unsigned)f2bf(acc[m][n][1] + bsv) << 16);
          pk.y = (unsigned)f2bf(acc[m][n][2] + bsv) | ((unsigned)f2bf(acc[m][n][3] + bsv) << 16);
          *(uint2*)(o + ((size_t)bi * DD + c2) * SS + si) = pk;
        }
      }
    }
  }
}

// ---------------- fused MFMA attention: 64-row i-tiles, fp16 score LDS ----------------
// 2048 blocks (8 itiles x 256 bh), longest itiles first (LPT).
// K AND V fragments direct from global (per-(b,h) slices L2-shared by the 8
// same-bh blocks, which land in the same XCD slot). Each wave's sc_s writes
// are private to its (row-block, col-block) region -> QK phase is barrier-free.
// Only 2 barriers per block: scores->softmax, softmax->PV.
__global__ __launch_bounds__(512) void k_attn(
    const unsigned short* __restrict__ Q, const unsigned short* __restrict__ Vt,
    const float* __restrict__ gam, unsigned short* __restrict__ AO,
    float* __restrict__ scores_out) {
  __shared__ _Float16 sc_s[64][520];       // 66560 B, 2 blk/CU

  const int tid = threadIdx.x;
  const int lane = tid & 63;
  const int w = tid >> 6;
  const int wr = w & 3;        // 16-row block
  const int wc = w >> 2;       // 32-col/dim block
  const int fr = lane & 15, fq = lane >> 4;

  const int itile = 7 - (blockIdx.x >> 8);    // 7..0: longest first
  const int bh = blockIdx.x & 255;
  const int b = bh >> 4;
  const int h = bh & 15;
  const int i0 = itile * 64;
  const int njt = itile + 1;                  // 1..8
  const int jcap = njt * 64;

  const unsigned short* Qb = Q + (size_t)b * SS * DD + h * DHH;
  const unsigned short* Vtb = Vt + ((size_t)b * DD + h * DHH) * SS;
  const float gneg = -fabsf(gam[h]);

  // Q fragments: loop-invariant, direct global -> registers
  const unsigned short* qrow = Qb + (size_t)(i0 + wr * 16 + fr) * DD;
  short8 a0 = *(const short8*)(qrow + fq * 8);
  short8 a1 = *(const short8*)(qrow + 32 + fq * 8);

  // ---- QK^T: K fragments direct from global, 1-tile prefetch, NO barriers ----
  const unsigned short* kb0 = Qb + (size_t)(wc * 32 + fr) * DD;
  const unsigned short* kb1 = Qb + (size_t)(wc * 32 + 16 + fr) * DD;
  short8 b00 = *(const short8*)(kb0 + fq * 8);
  short8 b01 = *(const short8*)(kb0 + 32 + fq * 8);
  short8 b10 = *(const short8*)(kb1 + fq * 8);
  short8 b11 = *(const short8*)(kb1 + 32 + fq * 8);
  for (int jt = 0; jt < njt; ++jt) {
    short8 n00 = b00, n01 = b01, n10 = b10, n11 = b11;
    if (jt + 1 < njt) {
      const size_t off = (size_t)(jt + 1) * 64 * DD;
      n00 = *(const short8*)(kb0 + off + fq * 8);
      n01 = *(const short8*)(kb0 + off + 32 + fq * 8);
      n10 = *(const short8*)(kb1 + off + fq * 8);
      n11 = *(const short8*)(kb1 + off + 32 + fq * 8);
    }
    f32x4 s0 = {}, s1 = {};
    __builtin_amdgcn_s_setprio(1);
    s0 = __builtin_amdgcn_mfma_f32_16x16x32_bf16(a0, b00, s0, 0, 0, 0);
    s0 = __builtin_amdgcn_mfma_f32_16x16x32_bf16(a1, b01, s0, 0, 0, 0);
    s1 = __builtin_amdgcn_mfma_f32_16x16x32_bf16(a0, b10, s1, 0, 0, 0);
    s1 = __builtin_amdgcn_mfma_f32_16x16x32_bf16(a1, b11, s1, 0, 0, 0);
    __builtin_amdgcn_s_setprio(0);

#pragma unroll
    for (int n = 0; n < 2; ++n) {
      const int j = jt * 64 + wc * 32 + n * 16 + fr;
#pragma unroll
      for (int r = 0; r < 4; ++r) {
        const int row = wr * 16 + fq * 4 + r;
        const float val = (n ? s1[r] : s0[r]) * 0.125f;
        sc_s[row][j] = (j < i0 + row) ? (_Float16)val : (_Float16)(-65504.0f);
      }
    }
    b00 = n00; b01 = n01; b10 = n10; b11 = n11;
  }
  __syncthreads();   // all scores visible

  if (itile >= 4) {
    // ---- full-wave softmax, 8 passes ----
    const int jb = lane << 3;
#pragma unroll 2
    for (int q = 0; q < 8; ++q) {
      const int r_i = w * 8 + q;
      const int gi = i0 + r_i;
      half8 hv = *(const half8*)(&sc_s[r_i][0] + jb);
      float sc[8];
#pragma unroll
      for (int c = 0; c < 8; ++c) sc[c] = (float)hv[c];
#pragma unroll
      for (int c = 0; c < 8; ++c)
        if (jb + c >= jcap) sc[c] = -1e30f;

      // softmax#1: max-free (ratio-invariant)
      float p[8];
      float lsum = 0.0f;
#pragma unroll
      for (int c = 0; c < 8; ++c) {
        p[c] = __expf(sc[c]);
        lsum += p[c];
      }

      float xs = lsum;
#pragma unroll
      for (int off = 1; off < 64; off <<= 1) {
        float y = __shfl_up(xs, off);
        if (lane >= off) xs += y;
      }
      const float tot = __shfl(xs, 63);
      const float inv = 1.0f / tot;
      float run = xs - lsum;

      // softmax#2 UNSHIFTED: s2 in [-30,30] -> exp fp32-safe.
      float s2[8];
      float m2l = -3e38f;
#pragma unroll
      for (int c = 0; c < 8; ++c) {
        run += p[c];
        float cum = run * inv;
        float dist = sqrtf(fmaxf((1.0f - cum) * (float)(gi - (jb + c)), 0.0f));
        float te = __expf(gneg * dist);
        te = fminf(fmaxf(te, 1e-5f), 1e5f);
        s2[c] = sc[c] * te;
        m2l = fmaxf(m2l, s2[c]);
      }
      float e[8];
      float ls2 = 0.0f;
#pragma unroll
      for (int c = 0; c < 8; ++c) {
        e[c] = __expf(s2[c]);
        ls2 += e[c];
      }
      const float m2 = wave_max(m2l);
      const float tot2 = wave_sum(ls2);
      const float rr = tot2 * __expf(-m2);
      const float mult = fminf(rr, 5.0f) / tot2;

      float av[8];
#pragma unroll
      for (int c = 0; c < 8; ++c) av[c] = (gi == 0) ? 0.0f : e[c] * mult;

      if (scores_out) {
        float* so = scores_out + ((size_t)(b * HH + h) * SS + gi) * SS + jb;
        *(float4*)(so) = make_float4(av[0], av[1], av[2], av[3]);
        *(float4*)(so + 4) = make_float4(av[4], av[5], av[6], av[7]);
      }

      short8 pk;
#pragma unroll
      for (int c = 0; c < 8; ++c) pk[c] = (short)f2bf(av[c]);
      *(short8*)((unsigned short*)&sc_s[r_i][0] + jb) = pk;
    }
  } else {
    // ---- half-wave softmax, 4 passes (jcap <= 256) ----
    const int half = lane >> 5;
    const int ll = lane & 31;
    const int jb = ll << 3;
    for (int q = 0; q < 4; ++q) {
      const int r_i = w * 8 + q * 2 + half;
      const int gi = i0 + r_i;
      half8 hv = *(const half8*)(&sc_s[r_i][0] + jb);
      float sc[8];
#pragma unroll
      for (int c = 0; c < 8; ++c) sc[c] = (float)hv[c];
#pragma unroll
      for (int c = 0; c < 8; ++c)
        if (jb + c >= jcap) sc[c] = -1e30f;

      // softmax#1: max-free
      float p[8];
      float lsum = 0.0f;
#pragma unroll
      for (int c = 0; c < 8; ++c) {
        p[c] = __expf(sc[c]);
        lsum += p[c];
      }

      float xs = lsum;
#pragma unroll
      for (int off = 1; off < 32; off <<= 1) {
        float y = __shfl_up(xs, off, 32);
        if (ll >= off) xs += y;
      }
      const float tot = __shfl(xs, 31, 32);
      const float inv = 1.0f / tot;
      float run = xs - lsum;

      // softmax#2 UNSHIFTED
      float s2[8];
      float m2l = -3e38f;
#pragma unroll
      for (int c = 0; c < 8; ++c) {
        run += p[c];
        float cum = run * inv;
        float dist = sqrtf(fmaxf((1.0f - cum) * (float)(gi - (jb + c)), 0.0f));
        float te = __expf(gneg * dist);
        te = fminf(fmaxf(te, 1e-5f), 1e5f);
        s2[c] = sc[c] * te;
        m2l = fmaxf(m2l, s2[c]);
      }
      float e[8];
      float ls2 = 0.0f;
#pragma unroll
      for (int c = 0; c < 8; ++c) {
        e[c] = __expf(s2[c]);
        ls2 += e[c];
      }
      const float m2 = half_max(m2l);
      const float tot2 = half_sum(ls2);
      const float rr = tot2 * __expf(-m2);
      const float mult = fminf(rr, 5.0f) / tot2;

      float av[8];
#pragma unroll
      for (int c = 0; c < 8; ++c) av[c] = (gi == 0) ? 0.0f : e[c] * mult;

      if (scores_out) {
        float* so = scores_out + ((size_t)(b * HH + h) * SS + gi) * SS + jb;
        *(float4*)(so) = make_float4(av[0], av[1], av[2], av[3]);
        *(float4*)(so + 4) = make_float4(av[4], av[5], av[6], av[7]);
        *(float4*)(so + 256) = make_float4(0.f, 0.f, 0.f, 0.f);
        *(float4*)(so + 260) = make_float4(0.f, 0.f, 0.f, 0.f);
      }

      short8 pk;
#pragma unroll
      for (int c = 0; c < 8; ++c) pk[c] = (short)f2bf(av[c]);
      *(short8*)((unsigned short*)&sc_s[r_i][0] + jb) = pk;
    }
  }
  __syncthreads();   // attn bf16 visible to all waves

  // ---- PV: V fragments direct from global (L2-resident), NO barriers ----
  const unsigned short* vb0 = Vtb + (size_t)(wc * 32 + fr) * SS;
  const unsigned short* vb1 = Vtb + (size_t)(wc * 32 + 16 + fr) * SS;
  short8 c00 = *(const short8*)(vb0 + fq * 8);
  short8 c01 = *(const short8*)(vb0 + 32 + fq * 8);
  short8 c10 = *(const short8*)(vb1 + fq * 8);
  short8 c11 = *(const short8*)(vb1 + 32 + fq * 8);
  f32x4 o0 = {}, o1 = {};
  for (int jt = 0; jt < njt; ++jt) {
    short8 n00 = c00, n01 = c01, n10 = c10, n11 = c11;
    if (jt + 1 < njt) {
      const int off = (jt + 1) * 64;
      n00 = *(const short8*)(vb0 + off + fq * 8);
      n01 = *(const short8*)(vb0 + off + 32 + fq * 8);
      n10 = *(const short8*)(vb1 + off + fq * 8);
      n11 = *(const short8*)(vb1 + off + 32 + fq * 8);
    }
    const unsigned short* arow = (const unsigned short*)&sc_s[wr * 16 + fr][0];
    short8 pa0 = *(const short8*)(arow + jt * 64 + fq * 8);
    short8 pa1 = *(const short8*)(arow + jt * 64 + 32 + fq * 8);
    __builtin_amdgcn_s_setprio(1);
    o0 = __builtin_amdgcn_mfma_f32_16x16x32_bf16(pa0, c00, o0, 0, 0, 0);
    o0 = __builtin_amdgcn_mfma_f32_16x16x32_bf16(pa1, c01, o0, 0, 0, 0);
    o1 = __builtin_amdgcn_mfma_f32_16x16x32_bf16(pa0, c10, o1, 0, 0, 0);
    o1 = __builtin_amdgcn_mfma_f32_16x16x32_bf16(pa1, c11, o1, 0, 0, 0);
    __builtin_amdgcn_s_setprio(0);
    c00 = n00; c01 = n01; c10 = n10; c11 = n11;
  }

#pragma unroll
  for (int n = 0; n < 2; ++n) {
    const int d = h * DHH + wc * 32 + n * 16 + fr;
#pragma unroll
    for (int r = 0; r < 4; ++r) {
      const int row = i0 + wr * 16 + fq * 4 + r;
      AO[((size_t)b * SS + row) * DD + d] = f2bf(n ? o1[r] : o0[r]);
    }
  }
}

// ---------------- residual + layernorm, bf16 activations ----------------
__global__ __launch_bounds__(256) void k_res_ln(
    const unsigned short* __restrict__ x, const unsigned short* __restrict__ r,
    const float* __restrict__ w, const float* __restrict__ b,
    unsigned short* __restrict__ outb, float* __restrict__ outf) {
  __shared__ float red[4];
  const int row = blockIdx.x;
  const int tid = threadIdx.x;
  const int lane = tid & 63, wv = tid >> 6;
  uint2 xa = ((const uint2*)(x + (size_t)row * DD))[tid];
  float y0 = bf2f((unsigned short)xa.x);
  float y1 = bf2f((unsigned short)(xa.x >> 16));
  float y2 = bf2f((unsigned short)xa.y);
  float y3 = bf2f((unsigned short)(xa.y >> 16));
  if (r) {
    uint2 ra = ((const uint2*)(r + (size_t)row * DD))[tid];
    y0 += bf2f((unsigned short)ra.x);
    y1 += bf2f((unsigned short)(ra.x >> 16));
    y2 += bf2f((unsigned short)ra.y);
    y3 += bf2f((unsigned short)(ra.y >> 16));
  }
  float s = y0 + y1 + y2 + y3;
  s = wave_sum(s);
  if (lane == 0) red[wv] = s;
  __syncthreads();
  float mean = (red[0] + red[1] + red[2] + red[3]) * (1.0f / DD);
  __syncthreads();
  float d0 = y0 - mean, d1 = y1 - mean, d2 = y2 - mean, d3 = y3 - mean;
  float s2 = d0 * d0 + d1 * d1 + d2 * d2 + d3 * d3;
  s2 = wave_sum(s2);
  if (lane == 0) red[wv] = s2;
  __syncthreads();
  float var = (red[0] + red[1] + red[2] + red[3]) * (1.0f / DD);
  float rstd = rsqrtf(var + 1e-5f);
  float4 ww = ((const float4*)w)[tid];
  float4 bb = ((const float4*)b)[tid];
  float o0 = d0 * rstd * ww.x + bb.x;
  float o1 = d1 * rstd * ww.y + bb.y;
  float o2 = d2 * rstd * ww.z + bb.z;
  float o3 = d3 * rstd * ww.w + bb.w;
  if (outf) {
    ((float4*)(outf + (size_t)row * DD))[tid] = make_float4(o0, o1, o2, o3);
  } else {
    uint2 pk;
    pk.x = (unsigned)f2bf(o0) | ((unsigned)f2bf(o1) << 16);
    pk.y = (unsigned)f2bf(o2) | ((unsigned)f2bf(o3) << 16);
    ((uint2*)(outb + (size_t)row * DD))[tid] = pk;
  }
}

extern "C" void kernel_launch(void* const* d_in, const int* in_sizes, int n_in,
                              void* d_out, int out_size, void* d_ws, size_t ws_size,
                              hipStream_t stream) {
  (void)in_sizes; (void)n_in; (void)out_size; (void)ws_size;
  const float* x = (const float*)d_in[0];
  const float* Wq = (const float*)d_in[2];
  const float* bq = (const float*)d_in[3];
  const float* Wv = (const float*)d_in[4];
  const float* bv = (const float*)d_in[5];
  const float* Wo = (const float*)d_in[6];
  const float* bo = (const float*)d_in[7];
  const float* gam = (const float*)d_in[8];
  const float* lnw = (const float*)d_in[9];
  const float* lnb = (const float*)d_in[10];
  const float* flnw = (const float*)d_in[11];
  const float* flnb = (const float*)d_in[12];

  float* out0 = (float*)d_out;
  float* scores = out0 + (size_t)BB * SS * DD;
  const size_t BUF = (size_t)BB * SS * DD;
  const size_t WSZ = (size_t)LL * DD * DD;
  const size_t BHSS = (size_t)BB * HH * SS * SS;

  unsigned short* us = (unsigned short*)d_ws;
  unsigned short* Abf0 = us;
  unsigned short* Abf1 = us + BUF;
  unsigned short* Qbf = us + 2 * BUF;
  unsigned short* VtB = us + 3 * BUF;
  unsigned short* AObf = us + 4 * BUF;
  unsigned short* Pb = us + 5 * BUF;
  unsigned short* Wob = us + 6 * BUF;
  unsigned short* Wqvb = (unsigned short*)scores + (2 * BHSS - 2 * WSZ);

  const int M = BB * SS;

  k_w2bf_all<<<dim3(3 * WSZ / 1024), 256, 0, stream>>>(Wq, Wv, Wo, Wqvb, Wob);
  k_add_pe<<<dim3(BUF / 1024), 256, 0, stream>>>(x, Abf0);

  unsigned short* Acur = Abf0;
  unsigned short* Anx = Abf1;
  for (int l = 0; l < LL; ++l) {
    float* sc_dst = (l == LL - 1) ? scores : nullptr;
    k_gemm<3><<<dim3(1024), 256, 0, stream>>>(Acur, Wqvb + (size_t)l * 2048 * DD,
                                              bq + l * DD, bv + l * DD, Qbf, VtB);
    k_attn<<<dim3(BB * HH * 8), 512, 0, stream>>>(Qbf, VtB, gam + l * HH, AObf, sc_dst);
    k_gemm<0><<<dim3(512), 256, 0, stream>>>(AObf, Wob + (size_t)l * DD * DD,
                                             bo + l * DD, nullptr, Pb, nullptr);
    k_res_ln<<<dim3(M), 256, 0, stream>>>(Acur, Pb, lnw + l * DD, lnb + l * DD, Anx, nullptr);
    unsigned short* t = Acur; Acur = Anx; Anx = t;
  }
  k_res_ln<<<dim3(M), 256, 0, stream>>>(Acur, nullptr, flnw, flnb, nullptr, out0);
}

// Round 20
// 751.007 us; speedup vs baseline: 1.1025x; 1.1025x over previous
//
#include <hip/hip_runtime.h>
#include <hip/hip_bf16.h>

#define BB 16
#define SS 512
#define DD 1024
#define HH 16
#define LL 4
#define DHH 64
#define GK 1024

typedef __attribute__((ext_vector_type(8))) short short8;
typedef __attribute__((ext_vector_type(4))) float f32x4;
typedef __attribute__((ext_vector_type(8))) _Float16 half8;

__device__ __forceinline__ unsigned short f2bf(float f) {
  union { float f; unsigned int u; } v; v.f = f;
  unsigned int r = v.u + 0x7FFFu + ((v.u >> 16) & 1u);
  return (unsigned short)(r >> 16);
}
__device__ __forceinline__ float bf2f(unsigned short u) {
  union { unsigned int i; float f; } v; v.i = ((unsigned)u) << 16; return v.f;
}

__device__ __forceinline__ float wave_max(float v) {
#pragma unroll
  for (int off = 32; off > 0; off >>= 1) v = fmaxf(v, __shfl_xor(v, off));
  return v;
}
__device__ __forceinline__ float wave_sum(float v) {
#pragma unroll
  for (int off = 32; off > 0; off >>= 1) v += __shfl_xor(v, off);
  return v;
}
__device__ __forceinline__ float half_max(float v) {   // width-32 segment
#pragma unroll
  for (int off = 16; off > 0; off >>= 1) v = fmaxf(v, __shfl_xor(v, off));
  return v;
}
__device__ __forceinline__ float half_sum(float v) {
#pragma unroll
  for (int off = 16; off > 0; off >>= 1) v += __shfl_xor(v, off);
  return v;
}

// global -> LDS direct 16B copy. LDS dest is wave-uniform base + lane*16.
__device__ __forceinline__ void gl16(const void* g, void* l) {
  __builtin_amdgcn_global_load_lds(
      (const __attribute__((address_space(1))) unsigned int*)(uintptr_t)g,
      (__attribute__((address_space(3))) unsigned int*)(unsigned int)(uintptr_t)l,
      16, 0, 0);
}

// ---------------- all weights fp32 -> bf16 in ONE launch ----------------
__global__ __launch_bounds__(256) void k_w2bf_all(
    const float* __restrict__ wq, const float* __restrict__ wv,
    const float* __restrict__ wo, unsigned short* __restrict__ oqv,
    unsigned short* __restrict__ oo) {
  size_t i4 = ((size_t)blockIdx.x * 256 + threadIdx.x) * 4;
  const size_t QV = (size_t)2 * LL * DD * DD;
  const float* src;
  unsigned short* dst;
  if (i4 < QV) {
    size_t l = i4 >> 21;
    size_t r = i4 & ((1u << 21) - 1);
    src = (r < (1u << 20)) ? wq + (l << 20) + r
                           : wv + (l << 20) + (r - (1u << 20));
    dst = oqv + i4;
  } else {
    size_t j = i4 - QV;
    src = wo + j;
    dst = oo + j;
  }
  float4 v = *(const float4*)src;
  uint2 pk;
  pk.x = (unsigned)f2bf(v.x) | ((unsigned)f2bf(v.y) << 16);
  pk.y = (unsigned)f2bf(v.z) | ((unsigned)f2bf(v.w) << 16);
  *(uint2*)dst = pk;
}

// ---------------- q0 = bf16(x + positional encoding) ----------------
__global__ __launch_bounds__(256) void k_add_pe(const float* __restrict__ x,
                                                unsigned short* __restrict__ outb) {
  size_t i4 = ((size_t)blockIdx.x * 256 + threadIdx.x) * 4;
  int d0 = (int)(i4 & (DD - 1));
  int s = (int)((i4 >> 10) & (SS - 1));
  float4 xv = *(const float4*)(x + i4);
  int ip0 = d0 >> 1;
  float f0 = __expf((float)ip0 * -0.017988946039016f);
  float f1 = __expf((float)(ip0 + 1) * -0.017988946039016f);
  float s0v, c0v, s1v, c1v;
  __sincosf((float)s * f0, &s0v, &c0v);
  __sincosf((float)s * f1, &s1v, &c1v);
  float o0 = xv.x + s0v, o1 = xv.y + c0v, o2 = xv.z + s1v, o3 = xv.w + c1v;
  uint2 pk;
  pk.x = (unsigned)f2bf(o0) | ((unsigned)f2bf(o1) << 16);
  pk.y = (unsigned)f2bf(o2) | ((unsigned)f2bf(o3) << 16);
  *(uint2*)(outb + i4) = pk;
}

// ---------------- C = A[M,K]bf16 @ W[N,K]^T bf16 + bias ----------------
// MODE 0: bf16 [M,1024].
// MODE 3: fused QV (N=2048): col<1024 -> bf16 Qbf; col>=1024 -> transposed VtB.
// XCD L2-locality mapping: each XCD owns a contiguous 8-M-tile panel.
template <int MODE>
__global__ __launch_bounds__(256) void k_gemm(
    const unsigned short* __restrict__ A, const unsigned short* __restrict__ W,
    const float* __restrict__ bias, const float* __restrict__ bias2,
    void* __restrict__ out, void* __restrict__ out2) {
  __shared__ unsigned short As[2][128 * 32];
  __shared__ unsigned short Bs[2][128 * 32];
  const int tid = threadIdx.x;
  const int lane = tid & 63;
  const int w = tid >> 6;
  const int wr = w >> 1, wc = w & 1;
  const int fr = lane & 15, fq = lane >> 4;

  const int bid = blockIdx.x;
  const int bm = ((bid & 7) * 8 + ((bid >> 3) & 7)) * 128;
  const int bn = (bid >> 6) * 128;

  f32x4 acc[4][4] = {};

  const unsigned short* ga = A + (size_t)(bm + w * 16 + (lane >> 2)) * GK + (lane & 3) * 8;
  const unsigned short* gb = W + (size_t)(bn + w * 16 + (lane >> 2)) * GK + (lane & 3) * 8;

  auto STAGE = [&](int buf, int k0) {
    unsigned short* la = As[buf] + w * 512;
    unsigned short* lb = Bs[buf] + w * 512;
    gl16(ga + k0, la);
    gl16(ga + 64 * GK + k0, la + 2048);
    gl16(gb + k0, lb);
    gl16(gb + 64 * GK + k0, lb + 2048);
  };

  STAGE(0, 0);
  __syncthreads();
  int cur = 0;
  for (int k0 = 0; k0 < GK; k0 += 32) {
    if (k0 + 32 < GK) STAGE(cur ^ 1, k0 + 32);
    short8 af[4], bf[4];
#pragma unroll
    for (int m = 0; m < 4; ++m)
      af[m] = *(const short8*)(As[cur] + (wr * 64 + m * 16 + fr) * 32 + fq * 8);
#pragma unroll
    for (int n = 0; n < 4; ++n)
      bf[n] = *(const short8*)(Bs[cur] + (wc * 64 + n * 16 + fr) * 32 + fq * 8);
#pragma unroll
    for (int m = 0; m < 4; ++m)
#pragma unroll
      for (int n = 0; n < 4; ++n)
        acc[m][n] = __builtin_amdgcn_mfma_f32_16x16x32_bf16(af[m], bf[n], acc[m][n], 0, 0, 0);
    __syncthreads();
    cur ^= 1;
  }

#pragma unroll
  for (int m = 0; m < 4; ++m) {
    const int row0 = bm + wr * 64 + m * 16 + fq * 4;
#pragma unroll
    for (int n = 0; n < 4; ++n) {
      const int col = bn + wc * 64 + n * 16 + fr;
      if constexpr (MODE == 0) {
        const float bsv = bias[col];
        unsigned short* o = (unsigned short*)out;
#pragma unroll
        for (int r = 0; r < 4; ++r)
          o[(size_t)(row0 + r) * DD + col] = f2bf(acc[m][n][r] + bsv);
      } else {  // MODE 3: fused QV
        if (col < DD) {
          const float bsv = bias[col];
          unsigned short* o = (unsigned short*)out;
#pragma unroll
          for (int r = 0; r < 4; ++r)
            o[(size_t)(row0 + r) * DD + col] = f2bf(acc[m][n][r] + bsv);
        } else {
          const int c2 = col - DD;
          const float bsv = bias2[c2];
          unsigned short* o = (unsigned short*)out2;
          const int bi = row0 >> 9, si = row0 & (SS - 1);
          uint2 pk;
          pk.x = (unsigned)f2bf(acc[m][n][0] + bsv) | ((unsigned)f2bf(acc[m][n][1] + bsv) << 16);
          pk.y = (unsigned)f2bf(acc[m][n][2] + bsv) | ((unsigned)f2bf(acc[m][n][3] + bsv) << 16);
          *(uint2*)(o + ((size_t)bi * DD + c2) * SS + si) = pk;
        }
      }
    }
  }
}

// ---------------- fused MFMA attention: 64-row i-tiles, fp16 score LDS ----------------
// r18 structure: K cooperatively staged in LDS (first-touch coalesced) with
// register prefetch; V fragments DIRECT from global (L2-hot by PV time).
__global__ __launch_bounds__(512) void k_attn(
    const unsigned short* __restrict__ Q, const unsigned short* __restrict__ Vt,
    const float* __restrict__ gam, unsigned short* __restrict__ AO,
    float* __restrict__ scores_out) {
  __shared__ _Float16 sc_s[64][520];       // 66560 B
  __shared__ unsigned short KV[64][72];    //  9216 B => 75776 B, 2 blk/CU

  const int tid = threadIdx.x;
  const int lane = tid & 63;
  const int w = tid >> 6;
  const int wr = w & 3;        // 16-row block
  const int wc = w >> 2;       // 32-col/dim block
  const int fr = lane & 15, fq = lane >> 4;

  const int itile = 7 - (blockIdx.x >> 8);    // 7..0: longest first
  const int bh = blockIdx.x & 255;
  const int b = bh >> 4;
  const int h = bh & 15;
  const int i0 = itile * 64;
  const int njt = itile + 1;                  // 1..8
  const int jcap = njt * 64;

  const unsigned short* Qb = Q + (size_t)b * SS * DD + h * DHH;
  const unsigned short* Vtb = Vt + ((size_t)b * DD + h * DHH) * SS;
  const float gneg = -fabsf(gam[h]);

  const int srow = tid >> 3;
  const int sdb = (tid & 7) * 8;

  // Q fragments: loop-invariant, direct global -> registers
  const unsigned short* qrow = Qb + (size_t)(i0 + wr * 16 + fr) * DD;
  short8 a0 = *(const short8*)(qrow + fq * 8);
  short8 a1 = *(const short8*)(qrow + 32 + fq * 8);

  short8 kreg = *(const short8*)(Qb + (size_t)srow * DD + sdb);
  for (int jt = 0; jt < njt; ++jt) {
    *(short8*)&KV[srow][sdb] = kreg;
    if (jt + 1 < njt)
      kreg = *(const short8*)(Qb + (size_t)((jt + 1) * 64 + srow) * DD + sdb);
    __syncthreads();

    short8 b00 = *(const short8*)&KV[wc * 32 + fr][fq * 8];
    short8 b01 = *(const short8*)&KV[wc * 32 + fr][32 + fq * 8];
    short8 b10 = *(const short8*)&KV[wc * 32 + 16 + fr][fq * 8];
    short8 b11 = *(const short8*)&KV[wc * 32 + 16 + fr][32 + fq * 8];
    f32x4 s0 = {}, s1 = {};
    __builtin_amdgcn_s_setprio(1);
    s0 = __builtin_amdgcn_mfma_f32_16x16x32_bf16(a0, b00, s0, 0, 0, 0);
    s0 = __builtin_amdgcn_mfma_f32_16x16x32_bf16(a1, b01, s0, 0, 0, 0);
    s1 = __builtin_amdgcn_mfma_f32_16x16x32_bf16(a0, b10, s1, 0, 0, 0);
    s1 = __builtin_amdgcn_mfma_f32_16x16x32_bf16(a1, b11, s1, 0, 0, 0);
    __builtin_amdgcn_s_setprio(0);

#pragma unroll
    for (int n = 0; n < 2; ++n) {
      const int j = jt * 64 + wc * 32 + n * 16 + fr;
#pragma unroll
      for (int r = 0; r < 4; ++r) {
        const int row = wr * 16 + fq * 4 + r;
        const float val = (n ? s1[r] : s0[r]) * 0.125f;
        sc_s[row][j] = (j < i0 + row) ? (_Float16)val : (_Float16)(-65504.0f);
      }
    }
    __syncthreads();
  }

  if (itile >= 4) {
    // ---- full-wave softmax, 8 passes ----
    const int jb = lane << 3;
#pragma unroll 2
    for (int q = 0; q < 8; ++q) {
      const int r_i = w * 8 + q;
      const int gi = i0 + r_i;
      half8 hv = *(const half8*)(&sc_s[r_i][0] + jb);
      float sc[8];
#pragma unroll
      for (int c = 0; c < 8; ++c) sc[c] = (float)hv[c];
#pragma unroll
      for (int c = 0; c < 8; ++c)
        if (jb + c >= jcap) sc[c] = -1e30f;

      // softmax#1: max-free (ratio-invariant)
      float p[8];
      float lsum = 0.0f;
#pragma unroll
      for (int c = 0; c < 8; ++c) {
        p[c] = __expf(sc[c]);
        lsum += p[c];
      }

      float xs = lsum;
#pragma unroll
      for (int off = 1; off < 64; off <<= 1) {
        float y = __shfl_up(xs, off);
        if (lane >= off) xs += y;
      }
      const float tot = __shfl(xs, 63);
      const float inv = 1.0f / tot;
      float run = xs - lsum;

      // softmax#2 UNSHIFTED: s2 in [-30,30] -> exp fp32-safe.
      float s2[8];
      float m2l = -3e38f;
#pragma unroll
      for (int c = 0; c < 8; ++c) {
        run += p[c];
        float cum = run * inv;
        float dist = sqrtf(fmaxf((1.0f - cum) * (float)(gi - (jb + c)), 0.0f));
        float te = __expf(gneg * dist);
        te = fminf(fmaxf(te, 1e-5f), 1e5f);
        s2[c] = sc[c] * te;
        m2l = fmaxf(m2l, s2[c]);
      }
      float e[8];
      float ls2 = 0.0f;
#pragma unroll
      for (int c = 0; c < 8; ++c) {
        e[c] = __expf(s2[c]);
        ls2 += e[c];
      }
      const float m2 = wave_max(m2l);
      const float tot2 = wave_sum(ls2);
      const float rr = tot2 * __expf(-m2);
      const float mult = fminf(rr, 5.0f) / tot2;

      float av[8];
#pragma unroll
      for (int c = 0; c < 8; ++c) av[c] = (gi == 0) ? 0.0f : e[c] * mult;

      if (scores_out) {
        float* so = scores_out + ((size_t)(b * HH + h) * SS + gi) * SS + jb;
        *(float4*)(so) = make_float4(av[0], av[1], av[2], av[3]);
        *(float4*)(so + 4) = make_float4(av[4], av[5], av[6], av[7]);
      }

      short8 pk;
#pragma unroll
      for (int c = 0; c < 8; ++c) pk[c] = (short)f2bf(av[c]);
      *(short8*)((unsigned short*)&sc_s[r_i][0] + jb) = pk;
    }
  } else {
    // ---- half-wave softmax, 4 passes (jcap <= 256) ----
    const int half = lane >> 5;
    const int ll = lane & 31;
    const int jb = ll << 3;
    for (int q = 0; q < 4; ++q) {
      const int r_i = w * 8 + q * 2 + half;
      const int gi = i0 + r_i;
      half8 hv = *(const half8*)(&sc_s[r_i][0] + jb);
      float sc[8];
#pragma unroll
      for (int c = 0; c < 8; ++c) sc[c] = (float)hv[c];
#pragma unroll
      for (int c = 0; c < 8; ++c)
        if (jb + c >= jcap) sc[c] = -1e30f;

      // softmax#1: max-free
      float p[8];
      float lsum = 0.0f;
#pragma unroll
      for (int c = 0; c < 8; ++c) {
        p[c] = __expf(sc[c]);
        lsum += p[c];
      }

      float xs = lsum;
#pragma unroll
      for (int off = 1; off < 32; off <<= 1) {
        float y = __shfl_up(xs, off, 32);
        if (ll >= off) xs += y;
      }
      const float tot = __shfl(xs, 31, 32);
      const float inv = 1.0f / tot;
      float run = xs - lsum;

      // softmax#2 UNSHIFTED
      float s2[8];
      float m2l = -3e38f;
#pragma unroll
      for (int c = 0; c < 8; ++c) {
        run += p[c];
        float cum = run * inv;
        float dist = sqrtf(fmaxf((1.0f - cum) * (float)(gi - (jb + c)), 0.0f));
        float te = __expf(gneg * dist);
        te = fminf(fmaxf(te, 1e-5f), 1e5f);
        s2[c] = sc[c] * te;
        m2l = fmaxf(m2l, s2[c]);
      }
      float e[8];
      float ls2 = 0.0f;
#pragma unroll
      for (int c = 0; c < 8; ++c) {
        e[c] = __expf(s2[c]);
        ls2 += e[c];
      }
      const float m2 = half_max(m2l);
      const float tot2 = half_sum(ls2);
      const float rr = tot2 * __expf(-m2);
      const float mult = fminf(rr, 5.0f) / tot2;

      float av[8];
#pragma unroll
      for (int c = 0; c < 8; ++c) av[c] = (gi == 0) ? 0.0f : e[c] * mult;

      if (scores_out) {
        float* so = scores_out + ((size_t)(b * HH + h) * SS + gi) * SS + jb;
        *(float4*)(so) = make_float4(av[0], av[1], av[2], av[3]);
        *(float4*)(so + 4) = make_float4(av[4], av[5], av[6], av[7]);
        *(float4*)(so + 256) = make_float4(0.f, 0.f, 0.f, 0.f);
        *(float4*)(so + 260) = make_float4(0.f, 0.f, 0.f, 0.f);
      }

      short8 pk;
#pragma unroll
      for (int c = 0; c < 8; ++c) pk[c] = (short)f2bf(av[c]);
      *(short8*)((unsigned short*)&sc_s[r_i][0] + jb) = pk;
    }
  }
  __syncthreads();   // attn bf16 visible to all waves

  // ---- PV: V fragments direct from global (L2-resident), NO barriers ----
  const unsigned short* vb0 = Vtb + (size_t)(wc * 32 + fr) * SS;
  const unsigned short* vb1 = Vtb + (size_t)(wc * 32 + 16 + fr) * SS;
  short8 c00 = *(const short8*)(vb0 + fq * 8);
  short8 c01 = *(const short8*)(vb0 + 32 + fq * 8);
  short8 c10 = *(const short8*)(vb1 + fq * 8);
  short8 c11 = *(const short8*)(vb1 + 32 + fq * 8);
  f32x4 o0 = {}, o1 = {};
  for (int jt = 0; jt < njt; ++jt) {
    short8 n00 = c00, n01 = c01, n10 = c10, n11 = c11;
    if (jt + 1 < njt) {
      const int off = (jt + 1) * 64;
      n00 = *(const short8*)(vb0 + off + fq * 8);
      n01 = *(const short8*)(vb0 + off + 32 + fq * 8);
      n10 = *(const short8*)(vb1 + off + fq * 8);
      n11 = *(const short8*)(vb1 + off + 32 + fq * 8);
    }
    const unsigned short* arow = (const unsigned short*)&sc_s[wr * 16 + fr][0];
    short8 pa0 = *(const short8*)(arow + jt * 64 + fq * 8);
    short8 pa1 = *(const short8*)(arow + jt * 64 + 32 + fq * 8);
    __builtin_amdgcn_s_setprio(1);
    o0 = __builtin_amdgcn_mfma_f32_16x16x32_bf16(pa0, c00, o0, 0, 0, 0);
    o0 = __builtin_amdgcn_mfma_f32_16x16x32_bf16(pa1, c01, o0, 0, 0, 0);
    o1 = __builtin_amdgcn_mfma_f32_16x16x32_bf16(pa0, c10, o1, 0, 0, 0);
    o1 = __builtin_amdgcn_mfma_f32_16x16x32_bf16(pa1, c11, o1, 0, 0, 0);
    __builtin_amdgcn_s_setprio(0);
    c00 = n00; c01 = n01; c10 = n10; c11 = n11;
  }

#pragma unroll
  for (int n = 0; n < 2; ++n) {
    const int d = h * DHH + wc * 32 + n * 16 + fr;
#pragma unroll
    for (int r = 0; r < 4; ++r) {
      const int row = i0 + wr * 16 + fq * 4 + r;
      AO[((size_t)b * SS + row) * DD + d] = f2bf(n ? o1[r] : o0[r]);
    }
  }
}

// ---------------- residual + layernorm: ONE WAVE PER ROW (no barriers/LDS) ----------------
__global__ __launch_bounds__(256) void k_res_ln(
    const unsigned short* __restrict__ x, const unsigned short* __restrict__ r,
    const float* __restrict__ w, const float* __restrict__ b,
    unsigned short* __restrict__ outb, float* __restrict__ outf) {
  const int row = blockIdx.x * 4 + (threadIdx.x >> 6);
  const int lane = threadIdx.x & 63;
  const int e0 = lane * 8;          // elems [e0,e0+8) and [512+e0,512+e0+8)
  const size_t base = (size_t)row * DD;

  uint4 xa = *(const uint4*)(x + base + e0);
  uint4 xb = *(const uint4*)(x + base + 512 + e0);
  float y[16];
#pragma unroll
  for (int i = 0; i < 4; ++i) {
    unsigned ua = ((const unsigned*)&xa)[i];
    unsigned ub = ((const unsigned*)&xb)[i];
    y[2 * i] = bf2f((unsigned short)ua);
    y[2 * i + 1] = bf2f((unsigned short)(ua >> 16));
    y[8 + 2 * i] = bf2f((unsigned short)ub);
    y[8 + 2 * i + 1] = bf2f((unsigned short)(ub >> 16));
  }
  if (r) {
    uint4 ra = *(const uint4*)(r + base + e0);
    uint4 rb = *(const uint4*)(r + base + 512 + e0);
#pragma unroll
    for (int i = 0; i < 4; ++i) {
      unsigned ua = ((const unsigned*)&ra)[i];
      unsigned ub = ((const unsigned*)&rb)[i];
      y[2 * i] += bf2f((unsigned short)ua);
      y[2 * i + 1] += bf2f((unsigned short)(ua >> 16));
      y[8 + 2 * i] += bf2f((unsigned short)ub);
      y[8 + 2 * i + 1] += bf2f((unsigned short)(ub >> 16));
    }
  }
  float s = 0.0f;
#pragma unroll
  for (int i = 0; i < 16; ++i) s += y[i];
  const float mean = wave_sum(s) * (1.0f / DD);
  float s2 = 0.0f;
#pragma unroll
  for (int i = 0; i < 16; ++i) {
    y[i] -= mean;
    s2 += y[i] * y[i];
  }
  const float rstd = rsqrtf(wave_sum(s2) * (1.0f / DD) + 1e-5f);

  float4 w0 = *(const float4*)(w + e0);
  float4 w1 = *(const float4*)(w + e0 + 4);
  float4 w2 = *(const float4*)(w + 512 + e0);
  float4 w3 = *(const float4*)(w + 512 + e0 + 4);
  float4 b0 = *(const float4*)(b + e0);
  float4 b1 = *(const float4*)(b + e0 + 4);
  float4 b2 = *(const float4*)(b + 512 + e0);
  float4 b3 = *(const float4*)(b + 512 + e0 + 4);
  float o[16];
  const float* wf = (const float*)&w0;  // w0..w3 contiguous? not guaranteed; index explicitly
  (void)wf;
  o[0] = y[0] * rstd * w0.x + b0.x;  o[1] = y[1] * rstd * w0.y + b0.y;
  o[2] = y[2] * rstd * w0.z + b0.z;  o[3] = y[3] * rstd * w0.w + b0.w;
  o[4] = y[4] * rstd * w1.x + b1.x;  o[5] = y[5] * rstd * w1.y + b1.y;
  o[6] = y[6] * rstd * w1.z + b1.z;  o[7] = y[7] * rstd * w1.w + b1.w;
  o[8] = y[8] * rstd * w2.x + b2.x;  o[9] = y[9] * rstd * w2.y + b2.y;
  o[10] = y[10] * rstd * w2.z + b2.z; o[11] = y[11] * rstd * w2.w + b2.w;
  o[12] = y[12] * rstd * w3.x + b3.x; o[13] = y[13] * rstd * w3.y + b3.y;
  o[14] = y[14] * rstd * w3.z + b3.z; o[15] = y[15] * rstd * w3.w + b3.w;

  if (outf) {
    float* of = outf + base;
    *(float4*)(of + e0) = make_float4(o[0], o[1], o[2], o[3]);
    *(float4*)(of + e0 + 4) = make_float4(o[4], o[5], o[6], o[7]);
    *(float4*)(of + 512 + e0) = make_float4(o[8], o[9], o[10], o[11]);
    *(float4*)(of + 512 + e0 + 4) = make_float4(o[12], o[13], o[14], o[15]);
  } else {
    uint4 pa, pb;
    pa.x = (unsigned)f2bf(o[0]) | ((unsigned)f2bf(o[1]) << 16);
    pa.y = (unsigned)f2bf(o[2]) | ((unsigned)f2bf(o[3]) << 16);
    pa.z = (unsigned)f2bf(o[4]) | ((unsigned)f2bf(o[5]) << 16);
    pa.w = (unsigned)f2bf(o[6]) | ((unsigned)f2bf(o[7]) << 16);
    pb.x = (unsigned)f2bf(o[8]) | ((unsigned)f2bf(o[9]) << 16);
    pb.y = (unsigned)f2bf(o[10]) | ((unsigned)f2bf(o[11]) << 16);
    pb.z = (unsigned)f2bf(o[12]) | ((unsigned)f2bf(o[13]) << 16);
    pb.w = (unsigned)f2bf(o[14]) | ((unsigned)f2bf(o[15]) << 16);
    *(uint4*)(outb + base + e0) = pa;
    *(uint4*)(outb + base + 512 + e0) = pb;
  }
}

extern "C" void kernel_launch(void* const* d_in, const int* in_sizes, int n_in,
                              void* d_out, int out_size, void* d_ws, size_t ws_size,
                              hipStream_t stream) {
  (void)in_sizes; (void)n_in; (void)out_size; (void)ws_size;
  const float* x = (const float*)d_in[0];
  const float* Wq = (const float*)d_in[2];
  const float* bq = (const float*)d_in[3];
  const float* Wv = (const float*)d_in[4];
  const float* bv = (const float*)d_in[5];
  const float* Wo = (const float*)d_in[6];
  const float* bo = (const float*)d_in[7];
  const float* gam = (const float*)d_in[8];
  const float* lnw = (const float*)d_in[9];
  const float* lnb = (const float*)d_in[10];
  const float* flnw = (const float*)d_in[11];
  const float* flnb = (const float*)d_in[12];

  float* out0 = (float*)d_out;
  float* scores = out0 + (size_t)BB * SS * DD;
  const size_t BUF = (size_t)BB * SS * DD;
  const size_t WSZ = (size_t)LL * DD * DD;
  const size_t BHSS = (size_t)BB * HH * SS * SS;

  unsigned short* us = (unsigned short*)d_ws;
  unsigned short* Abf0 = us;
  unsigned short* Abf1 = us + BUF;
  unsigned short* Qbf = us + 2 * BUF;
  unsigned short* VtB = us + 3 * BUF;
  unsigned short* AObf = us + 4 * BUF;
  unsigned short* Pb = us + 5 * BUF;
  unsigned short* Wob = us + 6 * BUF;
  unsigned short* Wqvb = (unsigned short*)scores + (2 * BHSS - 2 * WSZ);

  const int M = BB * SS;

  k_w2bf_all<<<dim3(3 * WSZ / 1024), 256, 0, stream>>>(Wq, Wv, Wo, Wqvb, Wob);
  k_add_pe<<<dim3(BUF / 1024), 256, 0, stream>>>(x, Abf0);

  unsigned short* Acur = Abf0;
  unsigned short* Anx = Abf1;
  for (int l = 0; l < LL; ++l) {
    float* sc_dst = (l == LL - 1) ? scores : nullptr;
    k_gemm<3><<<dim3(1024), 256, 0, stream>>>(Acur, Wqvb + (size_t)l * 2048 * DD,
                                              bq + l * DD, bv + l * DD, Qbf, VtB);
    k_attn<<<dim3(BB * HH * 8), 512, 0, stream>>>(Qbf, VtB, gam + l * HH, AObf, sc_dst);
    k_gemm<0><<<dim3(512), 256, 0, stream>>>(AObf, Wob + (size_t)l * DD * DD,
                                             bo + l * DD, nullptr, Pb, nullptr);
    k_res_ln<<<dim3(M / 4), 256, 0, stream>>>(Acur, Pb, lnw + l * DD, lnb + l * DD, Anx, nullptr);
    unsigned short* t = Acur; Acur = Anx; Anx = t;
  }
  k_res_ln<<<dim3(M / 4), 256, 0, stream>>>(Acur, nullptr, flnw, flnb, nullptr, out0);
}

// Round 21
// 733.073 us; speedup vs baseline: 1.1295x; 1.0245x over previous
//
#include <hip/hip_runtime.h>
#include <hip/hip_bf16.h>

#define BB 16
#define SS 512
#define DD 1024
#define HH 16
#define LL 4
#define DHH 64
#define GK 1024

typedef __attribute__((ext_vector_type(8))) short short8;
typedef __attribute__((ext_vector_type(4))) float f32x4;
typedef __attribute__((ext_vector_type(8))) _Float16 half8;

__device__ __forceinline__ unsigned short f2bf(float f) {
  union { float f; unsigned int u; } v; v.f = f;
  unsigned int r = v.u + 0x7FFFu + ((v.u >> 16) & 1u);
  return (unsigned short)(r >> 16);
}
__device__ __forceinline__ float bf2f(unsigned short u) {
  union { unsigned int i; float f; } v; v.i = ((unsigned)u) << 16; return v.f;
}

__device__ __forceinline__ float wave_max(float v) {
#pragma unroll
  for (int off = 32; off > 0; off >>= 1) v = fmaxf(v, __shfl_xor(v, off));
  return v;
}
__device__ __forceinline__ float wave_sum(float v) {
#pragma unroll
  for (int off = 32; off > 0; off >>= 1) v += __shfl_xor(v, off);
  return v;
}
__device__ __forceinline__ float half_max(float v) {   // width-32 segment
#pragma unroll
  for (int off = 16; off > 0; off >>= 1) v = fmaxf(v, __shfl_xor(v, off));
  return v;
}
__device__ __forceinline__ float half_sum(float v) {
#pragma unroll
  for (int off = 16; off > 0; off >>= 1) v += __shfl_xor(v, off);
  return v;
}

// global -> LDS direct 16B copy. LDS dest is wave-uniform base + lane*16.
__device__ __forceinline__ void gl16(const void* g, void* l) {
  __builtin_amdgcn_global_load_lds(
      (const __attribute__((address_space(1))) unsigned int*)(uintptr_t)g,
      (__attribute__((address_space(3))) unsigned int*)(unsigned int)(uintptr_t)l,
      16, 0, 0);
}

// ---------------- all weights fp32 -> bf16 in ONE launch ----------------
__global__ __launch_bounds__(256) void k_w2bf_all(
    const float* __restrict__ wq, const float* __restrict__ wv,
    const float* __restrict__ wo, unsigned short* __restrict__ oqv,
    unsigned short* __restrict__ oo) {
  size_t i4 = ((size_t)blockIdx.x * 256 + threadIdx.x) * 4;
  const size_t QV = (size_t)2 * LL * DD * DD;
  const float* src;
  unsigned short* dst;
  if (i4 < QV) {
    size_t l = i4 >> 21;
    size_t r = i4 & ((1u << 21) - 1);
    src = (r < (1u << 20)) ? wq + (l << 20) + r
                           : wv + (l << 20) + (r - (1u << 20));
    dst = oqv + i4;
  } else {
    size_t j = i4 - QV;
    src = wo + j;
    dst = oo + j;
  }
  float4 v = *(const float4*)src;
  uint2 pk;
  pk.x = (unsigned)f2bf(v.x) | ((unsigned)f2bf(v.y) << 16);
  pk.y = (unsigned)f2bf(v.z) | ((unsigned)f2bf(v.w) << 16);
  *(uint2*)dst = pk;
}

// ---------------- q0 = bf16(x + positional encoding) ----------------
__global__ __launch_bounds__(256) void k_add_pe(const float* __restrict__ x,
                                                unsigned short* __restrict__ outb) {
  size_t i4 = ((size_t)blockIdx.x * 256 + threadIdx.x) * 4;
  int d0 = (int)(i4 & (DD - 1));
  int s = (int)((i4 >> 10) & (SS - 1));
  float4 xv = *(const float4*)(x + i4);
  int ip0 = d0 >> 1;
  float f0 = __expf((float)ip0 * -0.017988946039016f);
  float f1 = __expf((float)(ip0 + 1) * -0.017988946039016f);
  float s0v, c0v, s1v, c1v;
  __sincosf((float)s * f0, &s0v, &c0v);
  __sincosf((float)s * f1, &s1v, &c1v);
  float o0 = xv.x + s0v, o1 = xv.y + c0v, o2 = xv.z + s1v, o3 = xv.w + c1v;
  uint2 pk;
  pk.x = (unsigned)f2bf(o0) | ((unsigned)f2bf(o1) << 16);
  pk.y = (unsigned)f2bf(o2) | ((unsigned)f2bf(o3) << 16);
  *(uint2*)(outb + i4) = pk;
}

// ---------------- C = A[M,K]bf16 @ W[N,K]^T bf16 + bias ----------------
// MODE 0: bf16 [M,1024].
// MODE 3: fused QV (N=2048): col<1024 -> bf16 Qbf; col>=1024 -> transposed VtB.
// XCD L2-locality mapping; __launch_bounds__(256,4): cap 128 VGPR -> 4 blk/CU
// (LDS is only 32KB so VGPR was the occupancy limiter).
template <int MODE>
__global__ __launch_bounds__(256, 4) void k_gemm(
    const unsigned short* __restrict__ A, const unsigned short* __restrict__ W,
    const float* __restrict__ bias, const float* __restrict__ bias2,
    void* __restrict__ out, void* __restrict__ out2) {
  __shared__ unsigned short As[2][128 * 32];
  __shared__ unsigned short Bs[2][128 * 32];
  const int tid = threadIdx.x;
  const int lane = tid & 63;
  const int w = tid >> 6;
  const int wr = w >> 1, wc = w & 1;
  const int fr = lane & 15, fq = lane >> 4;

  const int bid = blockIdx.x;
  const int bm = ((bid & 7) * 8 + ((bid >> 3) & 7)) * 128;
  const int bn = (bid >> 6) * 128;

  f32x4 acc[4][4] = {};

  const unsigned short* ga = A + (size_t)(bm + w * 16 + (lane >> 2)) * GK + (lane & 3) * 8;
  const unsigned short* gb = W + (size_t)(bn + w * 16 + (lane >> 2)) * GK + (lane & 3) * 8;

  auto STAGE = [&](int buf, int k0) {
    unsigned short* la = As[buf] + w * 512;
    unsigned short* lb = Bs[buf] + w * 512;
    gl16(ga + k0, la);
    gl16(ga + 64 * GK + k0, la + 2048);
    gl16(gb + k0, lb);
    gl16(gb + 64 * GK + k0, lb + 2048);
  };

  STAGE(0, 0);
  __syncthreads();
  int cur = 0;
  for (int k0 = 0; k0 < GK; k0 += 32) {
    if (k0 + 32 < GK) STAGE(cur ^ 1, k0 + 32);
    short8 af[4], bf[4];
#pragma unroll
    for (int m = 0; m < 4; ++m)
      af[m] = *(const short8*)(As[cur] + (wr * 64 + m * 16 + fr) * 32 + fq * 8);
#pragma unroll
    for (int n = 0; n < 4; ++n)
      bf[n] = *(const short8*)(Bs[cur] + (wc * 64 + n * 16 + fr) * 32 + fq * 8);
#pragma unroll
    for (int m = 0; m < 4; ++m)
#pragma unroll
      for (int n = 0; n < 4; ++n)
        acc[m][n] = __builtin_amdgcn_mfma_f32_16x16x32_bf16(af[m], bf[n], acc[m][n], 0, 0, 0);
    __syncthreads();
    cur ^= 1;
  }

#pragma unroll
  for (int m = 0; m < 4; ++m) {
    const int row0 = bm + wr * 64 + m * 16 + fq * 4;
#pragma unroll
    for (int n = 0; n < 4; ++n) {
      const int col = bn + wc * 64 + n * 16 + fr;
      if constexpr (MODE == 0) {
        const float bsv = bias[col];
        unsigned short* o = (unsigned short*)out;
#pragma unroll
        for (int r = 0; r < 4; ++r)
          o[(size_t)(row0 + r) * DD + col] = f2bf(acc[m][n][r] + bsv);
      } else {  // MODE 3: fused QV
        if (col < DD) {
          const float bsv = bias[col];
          unsigned short* o = (unsigned short*)out;
#pragma unroll
          for (int r = 0; r < 4; ++r)
            o[(size_t)(row0 + r) * DD + col] = f2bf(acc[m][n][r] + bsv);
        } else {
          const int c2 = col - DD;
          const float bsv = bias2[c2];
          unsigned short* o = (unsigned short*)out2;
          const int bi = row0 >> 9, si = row0 & (SS - 1);
          uint2 pk;
          pk.x = (unsigned)f2bf(acc[m][n][0] + bsv) | ((unsigned)f2bf(acc[m][n][1] + bsv) << 16);
          pk.y = (unsigned)f2bf(acc[m][n][2] + bsv) | ((unsigned)f2bf(acc[m][n][3] + bsv) << 16);
          *(uint2*)(o + ((size_t)bi * DD + c2) * SS + si) = pk;
        }
      }
    }
  }
}

// ---------------- fused MFMA attention: 64-row i-tiles, fp16 score LDS ----------------
// r18/r20 structure: K cooperatively staged in LDS (first-touch coalesced) with
// register prefetch; V fragments DIRECT from global (L2-hot by PV time).
__global__ __launch_bounds__(512) void k_attn(
    const unsigned short* __restrict__ Q, const unsigned short* __restrict__ Vt,
    const float* __restrict__ gam, unsigned short* __restrict__ AO,
    float* __restrict__ scores_out) {
  __shared__ _Float16 sc_s[64][520];       // 66560 B
  __shared__ unsigned short KV[64][72];    //  9216 B => 75776 B, 2 blk/CU

  const int tid = threadIdx.x;
  const int lane = tid & 63;
  const int w = tid >> 6;
  const int wr = w & 3;        // 16-row block
  const int wc = w >> 2;       // 32-col/dim block
  const int fr = lane & 15, fq = lane >> 4;

  const int itile = 7 - (blockIdx.x >> 8);    // 7..0: longest first
  const int bh = blockIdx.x & 255;
  const int b = bh >> 4;
  const int h = bh & 15;
  const int i0 = itile * 64;
  const int njt = itile + 1;                  // 1..8
  const int jcap = njt * 64;

  const unsigned short* Qb = Q + (size_t)b * SS * DD + h * DHH;
  const unsigned short* Vtb = Vt + ((size_t)b * DD + h * DHH) * SS;
  const float gneg = -fabsf(gam[h]);

  const int srow = tid >> 3;
  const int sdb = (tid & 7) * 8;

  // Q fragments: loop-invariant, direct global -> registers
  const unsigned short* qrow = Qb + (size_t)(i0 + wr * 16 + fr) * DD;
  short8 a0 = *(const short8*)(qrow + fq * 8);
  short8 a1 = *(const short8*)(qrow + 32 + fq * 8);

  short8 kreg = *(const short8*)(Qb + (size_t)srow * DD + sdb);
  for (int jt = 0; jt < njt; ++jt) {
    *(short8*)&KV[srow][sdb] = kreg;
    if (jt + 1 < njt)
      kreg = *(const short8*)(Qb + (size_t)((jt + 1) * 64 + srow) * DD + sdb);
    __syncthreads();

    short8 b00 = *(const short8*)&KV[wc * 32 + fr][fq * 8];
    short8 b01 = *(const short8*)&KV[wc * 32 + fr][32 + fq * 8];
    short8 b10 = *(const short8*)&KV[wc * 32 + 16 + fr][fq * 8];
    short8 b11 = *(const short8*)&KV[wc * 32 + 16 + fr][32 + fq * 8];
    f32x4 s0 = {}, s1 = {};
    __builtin_amdgcn_s_setprio(1);
    s0 = __builtin_amdgcn_mfma_f32_16x16x32_bf16(a0, b00, s0, 0, 0, 0);
    s0 = __builtin_amdgcn_mfma_f32_16x16x32_bf16(a1, b01, s0, 0, 0, 0);
    s1 = __builtin_amdgcn_mfma_f32_16x16x32_bf16(a0, b10, s1, 0, 0, 0);
    s1 = __builtin_amdgcn_mfma_f32_16x16x32_bf16(a1, b11, s1, 0, 0, 0);
    __builtin_amdgcn_s_setprio(0);

#pragma unroll
    for (int n = 0; n < 2; ++n) {
      const int j = jt * 64 + wc * 32 + n * 16 + fr;
#pragma unroll
      for (int r = 0; r < 4; ++r) {
        const int row = wr * 16 + fq * 4 + r;
        const float val = (n ? s1[r] : s0[r]) * 0.125f;
        sc_s[row][j] = (j < i0 + row) ? (_Float16)val : (_Float16)(-65504.0f);
      }
    }
    __syncthreads();
  }

  if (itile >= 4) {
    // ---- full-wave softmax, 8 passes ----
    const int jb = lane << 3;
#pragma unroll 2
    for (int q = 0; q < 8; ++q) {
      const int r_i = w * 8 + q;
      const int gi = i0 + r_i;
      half8 hv = *(const half8*)(&sc_s[r_i][0] + jb);
      float sc[8];
#pragma unroll
      for (int c = 0; c < 8; ++c) sc[c] = (float)hv[c];
#pragma unroll
      for (int c = 0; c < 8; ++c)
        if (jb + c >= jcap) sc[c] = -1e30f;

      // softmax#1: max-free (ratio-invariant)
      float p[8];
      float lsum = 0.0f;
#pragma unroll
      for (int c = 0; c < 8; ++c) {
        p[c] = __expf(sc[c]);
        lsum += p[c];
      }

      float xs = lsum;
#pragma unroll
      for (int off = 1; off < 64; off <<= 1) {
        float y = __shfl_up(xs, off);
        if (lane >= off) xs += y;
      }
      const float tot = __shfl(xs, 63);
      const float inv = 1.0f / tot;
      float run = xs - lsum;

      // softmax#2 UNSHIFTED: s2 in [-30,30] -> exp fp32-safe.
      float s2[8];
      float m2l = -3e38f;
#pragma unroll
      for (int c = 0; c < 8; ++c) {
        run += p[c];
        float cum = run * inv;
        float dist = sqrtf(fmaxf((1.0f - cum) * (float)(gi - (jb + c)), 0.0f));
        float te = __expf(gneg * dist);
        te = fminf(fmaxf(te, 1e-5f), 1e5f);
        s2[c] = sc[c] * te;
        m2l = fmaxf(m2l, s2[c]);
      }
      float e[8];
      float ls2 = 0.0f;
#pragma unroll
      for (int c = 0; c < 8; ++c) {
        e[c] = __expf(s2[c]);
        ls2 += e[c];
      }
      const float m2 = wave_max(m2l);
      const float tot2 = wave_sum(ls2);
      const float rr = tot2 * __expf(-m2);
      const float mult = fminf(rr, 5.0f) / tot2;

      float av[8];
#pragma unroll
      for (int c = 0; c < 8; ++c) av[c] = (gi == 0) ? 0.0f : e[c] * mult;

      if (scores_out) {
        float* so = scores_out + ((size_t)(b * HH + h) * SS + gi) * SS + jb;
        *(float4*)(so) = make_float4(av[0], av[1], av[2], av[3]);
        *(float4*)(so + 4) = make_float4(av[4], av[5], av[6], av[7]);
      }

      short8 pk;
#pragma unroll
      for (int c = 0; c < 8; ++c) pk[c] = (short)f2bf(av[c]);
      *(short8*)((unsigned short*)&sc_s[r_i][0] + jb) = pk;
    }
  } else {
    // ---- half-wave softmax, 4 passes (jcap <= 256) ----
    const int half = lane >> 5;
    const int ll = lane & 31;
    const int jb = ll << 3;
    for (int q = 0; q < 4; ++q) {
      const int r_i = w * 8 + q * 2 + half;
      const int gi = i0 + r_i;
      half8 hv = *(const half8*)(&sc_s[r_i][0] + jb);
      float sc[8];
#pragma unroll
      for (int c = 0; c < 8; ++c) sc[c] = (float)hv[c];
#pragma unroll
      for (int c = 0; c < 8; ++c)
        if (jb + c >= jcap) sc[c] = -1e30f;

      // softmax#1: max-free
      float p[8];
      float lsum = 0.0f;
#pragma unroll
      for (int c = 0; c < 8; ++c) {
        p[c] = __expf(sc[c]);
        lsum += p[c];
      }

      float xs = lsum;
#pragma unroll
      for (int off = 1; off < 32; off <<= 1) {
        float y = __shfl_up(xs, off, 32);
        if (ll >= off) xs += y;
      }
      const float tot = __shfl(xs, 31, 32);
      const float inv = 1.0f / tot;
      float run = xs - lsum;

      // softmax#2 UNSHIFTED
      float s2[8];
      float m2l = -3e38f;
#pragma unroll
      for (int c = 0; c < 8; ++c) {
        run += p[c];
        float cum = run * inv;
        float dist = sqrtf(fmaxf((1.0f - cum) * (float)(gi - (jb + c)), 0.0f));
        float te = __expf(gneg * dist);
        te = fminf(fmaxf(te, 1e-5f), 1e5f);
        s2[c] = sc[c] * te;
        m2l = fmaxf(m2l, s2[c]);
      }
      float e[8];
      float ls2 = 0.0f;
#pragma unroll
      for (int c = 0; c < 8; ++c) {
        e[c] = __expf(s2[c]);
        ls2 += e[c];
      }
      const float m2 = half_max(m2l);
      const float tot2 = half_sum(ls2);
      const float rr = tot2 * __expf(-m2);
      const float mult = fminf(rr, 5.0f) / tot2;

      float av[8];
#pragma unroll
      for (int c = 0; c < 8; ++c) av[c] = (gi == 0) ? 0.0f : e[c] * mult;

      if (scores_out) {
        float* so = scores_out + ((size_t)(b * HH + h) * SS + gi) * SS + jb;
        *(float4*)(so) = make_float4(av[0], av[1], av[2], av[3]);
        *(float4*)(so + 4) = make_float4(av[4], av[5], av[6], av[7]);
        *(float4*)(so + 256) = make_float4(0.f, 0.f, 0.f, 0.f);
        *(float4*)(so + 260) = make_float4(0.f, 0.f, 0.f, 0.f);
      }

      short8 pk;
#pragma unroll
      for (int c = 0; c < 8; ++c) pk[c] = (short)f2bf(av[c]);
      *(short8*)((unsigned short*)&sc_s[r_i][0] + jb) = pk;
    }
  }
  __syncthreads();   // attn bf16 visible to all waves

  // ---- PV: V fragments direct from global (L2-resident), NO barriers ----
  const unsigned short* vb0 = Vtb + (size_t)(wc * 32 + fr) * SS;
  const unsigned short* vb1 = Vtb + (size_t)(wc * 32 + 16 + fr) * SS;
  short8 c00 = *(const short8*)(vb0 + fq * 8);
  short8 c01 = *(const short8*)(vb0 + 32 + fq * 8);
  short8 c10 = *(const short8*)(vb1 + fq * 8);
  short8 c11 = *(const short8*)(vb1 + 32 + fq * 8);
  f32x4 o0 = {}, o1 = {};
  for (int jt = 0; jt < njt; ++jt) {
    short8 n00 = c00, n01 = c01, n10 = c10, n11 = c11;
    if (jt + 1 < njt) {
      const int off = (jt + 1) * 64;
      n00 = *(const short8*)(vb0 + off + fq * 8);
      n01 = *(const short8*)(vb0 + off + 32 + fq * 8);
      n10 = *(const short8*)(vb1 + off + fq * 8);
      n11 = *(const short8*)(vb1 + off + 32 + fq * 8);
    }
    const unsigned short* arow = (const unsigned short*)&sc_s[wr * 16 + fr][0];
    short8 pa0 = *(const short8*)(arow + jt * 64 + fq * 8);
    short8 pa1 = *(const short8*)(arow + jt * 64 + 32 + fq * 8);
    __builtin_amdgcn_s_setprio(1);
    o0 = __builtin_amdgcn_mfma_f32_16x16x32_bf16(pa0, c00, o0, 0, 0, 0);
    o0 = __builtin_amdgcn_mfma_f32_16x16x32_bf16(pa1, c01, o0, 0, 0, 0);
    o1 = __builtin_amdgcn_mfma_f32_16x16x32_bf16(pa0, c10, o1, 0, 0, 0);
    o1 = __builtin_amdgcn_mfma_f32_16x16x32_bf16(pa1, c11, o1, 0, 0, 0);
    __builtin_amdgcn_s_setprio(0);
    c00 = n00; c01 = n01; c10 = n10; c11 = n11;
  }

#pragma unroll
  for (int n = 0; n < 2; ++n) {
    const int d = h * DHH + wc * 32 + n * 16 + fr;
#pragma unroll
    for (int r = 0; r < 4; ++r) {
      const int row = i0 + wr * 16 + fq * 4 + r;
      AO[((size_t)b * SS + row) * DD + d] = f2bf(n ? o1[r] : o0[r]);
    }
  }
}

// ---------------- residual + layernorm: ONE WAVE PER ROW (no barriers/LDS) ----------------
__global__ __launch_bounds__(256) void k_res_ln(
    const unsigned short* __restrict__ x, const unsigned short* __restrict__ r,
    const float* __restrict__ w, const float* __restrict__ b,
    unsigned short* __restrict__ outb, float* __restrict__ outf) {
  const int row = blockIdx.x * 4 + (threadIdx.x >> 6);
  const int lane = threadIdx.x & 63;
  const int e0 = lane * 8;          // elems [e0,e0+8) and [512+e0,512+e0+8)
  const size_t base = (size_t)row * DD;

  uint4 xa = *(const uint4*)(x + base + e0);
  uint4 xb = *(const uint4*)(x + base + 512 + e0);
  float y[16];
#pragma unroll
  for (int i = 0; i < 4; ++i) {
    unsigned ua = ((const unsigned*)&xa)[i];
    unsigned ub = ((const unsigned*)&xb)[i];
    y[2 * i] = bf2f((unsigned short)ua);
    y[2 * i + 1] = bf2f((unsigned short)(ua >> 16));
    y[8 + 2 * i] = bf2f((unsigned short)ub);
    y[8 + 2 * i + 1] = bf2f((unsigned short)(ub >> 16));
  }
  if (r) {
    uint4 ra = *(const uint4*)(r + base + e0);
    uint4 rb = *(const uint4*)(r + base + 512 + e0);
#pragma unroll
    for (int i = 0; i < 4; ++i) {
      unsigned ua = ((const unsigned*)&ra)[i];
      unsigned ub = ((const unsigned*)&rb)[i];
      y[2 * i] += bf2f((unsigned short)ua);
      y[2 * i + 1] += bf2f((unsigned short)(ua >> 16));
      y[8 + 2 * i] += bf2f((unsigned short)ub);
      y[8 + 2 * i + 1] += bf2f((unsigned short)(ub >> 16));
    }
  }
  float s = 0.0f;
#pragma unroll
  for (int i = 0; i < 16; ++i) s += y[i];
  const float mean = wave_sum(s) * (1.0f / DD);
  float s2 = 0.0f;
#pragma unroll
  for (int i = 0; i < 16; ++i) {
    y[i] -= mean;
    s2 += y[i] * y[i];
  }
  const float rstd = rsqrtf(wave_sum(s2) * (1.0f / DD) + 1e-5f);

  float4 w0 = *(const float4*)(w + e0);
  float4 w1 = *(const float4*)(w + e0 + 4);
  float4 w2 = *(const float4*)(w + 512 + e0);
  float4 w3 = *(const float4*)(w + 512 + e0 + 4);
  float4 b0 = *(const float4*)(b + e0);
  float4 b1 = *(const float4*)(b + e0 + 4);
  float4 b2 = *(const float4*)(b + 512 + e0);
  float4 b3 = *(const float4*)(b + 512 + e0 + 4);
  float o[16];
  o[0] = y[0] * rstd * w0.x + b0.x;  o[1] = y[1] * rstd * w0.y + b0.y;
  o[2] = y[2] * rstd * w0.z + b0.z;  o[3] = y[3] * rstd * w0.w + b0.w;
  o[4] = y[4] * rstd * w1.x + b1.x;  o[5] = y[5] * rstd * w1.y + b1.y;
  o[6] = y[6] * rstd * w1.z + b1.z;  o[7] = y[7] * rstd * w1.w + b1.w;
  o[8] = y[8] * rstd * w2.x + b2.x;  o[9] = y[9] * rstd * w2.y + b2.y;
  o[10] = y[10] * rstd * w2.z + b2.z; o[11] = y[11] * rstd * w2.w + b2.w;
  o[12] = y[12] * rstd * w3.x + b3.x; o[13] = y[13] * rstd * w3.y + b3.y;
  o[14] = y[14] * rstd * w3.z + b3.z; o[15] = y[15] * rstd * w3.w + b3.w;

  if (outf) {
    float* of = outf + base;
    *(float4*)(of + e0) = make_float4(o[0], o[1], o[2], o[3]);
    *(float4*)(of + e0 + 4) = make_float4(o[4], o[5], o[6], o[7]);
    *(float4*)(of + 512 + e0) = make_float4(o[8], o[9], o[10], o[11]);
    *(float4*)(of + 512 + e0 + 4) = make_float4(o[12], o[13], o[14], o[15]);
  } else {
    uint4 pa, pb;
    pa.x = (unsigned)f2bf(o[0]) | ((unsigned)f2bf(o[1]) << 16);
    pa.y = (unsigned)f2bf(o[2]) | ((unsigned)f2bf(o[3]) << 16);
    pa.z = (unsigned)f2bf(o[4]) | ((unsigned)f2bf(o[5]) << 16);
    pa.w = (unsigned)f2bf(o[6]) | ((unsigned)f2bf(o[7]) << 16);
    pb.x = (unsigned)f2bf(o[8]) | ((unsigned)f2bf(o[9]) << 16);
    pb.y = (unsigned)f2bf(o[10]) | ((unsigned)f2bf(o[11]) << 16);
    pb.z = (unsigned)f2bf(o[12]) | ((unsigned)f2bf(o[13]) << 16);
    pb.w = (unsigned)f2bf(o[14]) | ((unsigned)f2bf(o[15]) << 16);
    *(uint4*)(outb + base + e0) = pa;
    *(uint4*)(outb + base + 512 + e0) = pb;
  }
}

extern "C" void kernel_launch(void* const* d_in, const int* in_sizes, int n_in,
                              void* d_out, int out_size, void* d_ws, size_t ws_size,
                              hipStream_t stream) {
  (void)in_sizes; (void)n_in; (void)out_size; (void)ws_size;
  const float* x = (const float*)d_in[0];
  const float* Wq = (const float*)d_in[2];
  const float* bq = (const float*)d_in[3];
  const float* Wv = (const float*)d_in[4];
  const float* bv = (const float*)d_in[5];
  const float* Wo = (const float*)d_in[6];
  const float* bo = (const float*)d_in[7];
  const float* gam = (const float*)d_in[8];
  const float* lnw = (const float*)d_in[9];
  const float* lnb = (const float*)d_in[10];
  const float* flnw = (const float*)d_in[11];
  const float* flnb = (const float*)d_in[12];

  float* out0 = (float*)d_out;
  float* scores = out0 + (size_t)BB * SS * DD;
  const size_t BUF = (size_t)BB * SS * DD;
  const size_t WSZ = (size_t)LL * DD * DD;
  const size_t BHSS = (size_t)BB * HH * SS * SS;

  unsigned short* us = (unsigned short*)d_ws;
  unsigned short* Abf0 = us;
  unsigned short* Abf1 = us + BUF;
  unsigned short* Qbf = us + 2 * BUF;
  unsigned short* VtB = us + 3 * BUF;
  unsigned short* AObf = us + 4 * BUF;
  unsigned short* Pb = us + 5 * BUF;
  unsigned short* Wob = us + 6 * BUF;
  unsigned short* Wqvb = (unsigned short*)scores + (2 * BHSS - 2 * WSZ);

  const int M = BB * SS;

  k_w2bf_all<<<dim3(3 * WSZ / 1024), 256, 0, stream>>>(Wq, Wv, Wo, Wqvb, Wob);
  k_add_pe<<<dim3(BUF / 1024), 256, 0, stream>>>(x, Abf0);

  unsigned short* Acur = Abf0;
  unsigned short* Anx = Abf1;
  for (int l = 0; l < LL; ++l) {
    float* sc_dst = (l == LL - 1) ? scores : nullptr;
    k_gemm<3><<<dim3(1024), 256, 0, stream>>>(Acur, Wqvb + (size_t)l * 2048 * DD,
                                              bq + l * DD, bv + l * DD, Qbf, VtB);
    k_attn<<<dim3(BB * HH * 8), 512, 0, stream>>>(Qbf, VtB, gam + l * HH, AObf, sc_dst);
    k_gemm<0><<<dim3(512), 256, 0, stream>>>(AObf, Wob + (size_t)l * DD * DD,
                                             bo + l * DD, nullptr, Pb, nullptr);
    k_res_ln<<<dim3(M / 4), 256, 0, stream>>>(Acur, Pb, lnw + l * DD, lnb + l * DD, Anx, nullptr);
    unsigned short* t = Acur; Acur = Anx; Anx = t;
  }
  k_res_ln<<<dim3(M / 4), 256, 0, stream>>>(Acur, nullptr, flnw, flnb, nullptr, out0);
}